// Round 2
// baseline (532.145 us; speedup 1.0000x reference)
//
#include <hip/hip_runtime.h>
#include <hip/hip_fp16.h>

namespace {
constexpr int kT = 32, kDQ = 128, kK = 8, kS = 4, kCTX = 16, kD = 257, kEVO = 8;
constexpr float kDT = 0.2f, kDAMP = 0.1f, kGAMMA = 10.0f, kEPS = 1e-8f;

typedef _Float16 half8 __attribute__((ext_vector_type(8)));
typedef float f32x4 __attribute__((ext_vector_type(4)));
typedef unsigned u32x4 __attribute__((ext_vector_type(4)));

__device__ __forceinline__ unsigned packh2(float lo, float hi) {
  __half l = __float2half(lo), h = __float2half(hi);
  return (unsigned)__half_as_ushort(l) | ((unsigned)__half_as_ushort(h) << 16);
}
__device__ __forceinline__ float fast_tanh(float x) {
  // 1 - 2/(e^{2x}+1); monotone, saturates to +-1, ~2ulp via __expf
  float e = __expf(2.f * x);
  return 1.f - 2.f / (e + 1.f);
}
}  // namespace

extern "C" __global__ void __launch_bounds__(1024)
seq_main(const int* __restrict__ inputs, const int* __restrict__ targets,
         const int* __restrict__ task_ids, const float* __restrict__ st0,
         const float* __restrict__ bit_emb, const float* __restrict__ task_u,
         const float* __restrict__ ctx_emb, const float* __restrict__ rw_g,
         const float* __restrict__ rb_g, const float* __restrict__ Wq_g,
         const float* __restrict__ Wc_g, const float* __restrict__ b_g,
         const float* __restrict__ A_g, float* __restrict__ ws) {
  const int tid = threadIdx.x, b = blockIdx.x;
  const int lane = tid & 63, w = tid >> 6;
  const int il = lane & 7;          // owned local i: global i = 8w + il
  const int own_i = 8 * w + il;
  const int g4 = lane >> 4;         // 0..3 (MFMA k-group)

  __shared__ __align__(16) float rw_l[kK * kS * kD];
  __shared__ __align__(16) float u4_l[4][kDQ];
  __shared__ __align__(16) float q_l[kDQ];
  __shared__ __align__(16) float p_l[kDQ];
  __shared__ __align__(16) unsigned tq_l[2][64];   // double-buffered tanh(q) fp16-packed
  __shared__ __align__(16) float wq_ctx2[2][kK];
  __shared__ __align__(16) float wlog_l[kK];
  __shared__ __align__(16) float chartw_l[kK];
  __shared__ float rb_l[kK * kS];
  __shared__ float lk_l[kK * kS];
  __shared__ float acc_l[64];
  __shared__ float s_l;

  // ---------- init: small tables ----------
  for (int idx = tid; idx < kK * kS * kD; idx += 1024) rw_l[idx] = rw_g[idx];
  if (tid < kK * kS) rb_l[tid] = rb_g[tid];
  if (tid == 0) s_l = st0[b * kD + 2 * kDQ];
  if (tid < 64) acc_l[tid] = 0.f;
  if (tid < 512) {
    int cb = tid >> 7, i = tid & 127;
    u4_l[cb][i] = tanhf(bit_emb[(cb & 1) * kDQ + i]) + tanhf(task_u[(cb >> 1) * kDQ + i]);
  }
  if (tid < 16) {
    int tk = tid >> 3, kk = tid & 7;
    float s = b_g[kk];
    #pragma unroll
    for (int c = 0; c < kCTX; c++) s += tanhf(ctx_emb[tk * kCTX + c]) * Wc_g[c * kK + kk];
    wq_ctx2[tk][kk] = s;
  }
  // router weights for the 512-thread q@Wq phase (Wq is [DQ][K])
  float wpx = 0.f, wpy = 0.f;
  if (tid < 512) {
    int kk = tid >> 6, l2 = tid & 63;
    wpx = Wq_g[(2 * l2) * kK + kk];
    wpy = Wq_g[(2 * l2 + 1) * kK + kk];
  }

  // ---------- A fragments in registers (fp16), MFMA row mapping ----------
  // row rho = mt*16 + m, m = lane&15 on the A side:
  //   kA = (m&3) + 4*((m>>3)&1), i = 8w + 2mt + ((m>>2)&1)
  const int kA = (lane & 3) + 4 * ((lane >> 3) & 1);
  const int ipar = (lane >> 2) & 1;
  u32x4 afr[4][4];
  #pragma unroll
  for (int mt = 0; mt < 4; mt++) {
    const float* arow = A_g + ((size_t)kA * kDQ + (8 * w + 2 * mt + ipar)) * kDQ;
    #pragma unroll
    for (int ks = 0; ks < 4; ks++) {
      const float4* p4 = reinterpret_cast<const float4*>(arow + 32 * ks + 8 * g4);
      float4 f0 = p4[0], f1 = p4[1];
      u32x4 v;
      v.x = packh2(f0.x, f0.y); v.y = packh2(f0.z, f0.w);
      v.z = packh2(f1.x, f1.y); v.w = packh2(f1.z, f1.w);
      afr[mt][ks] = v;
    }
  }

  // ---------- per-lane persistent state ----------
  float q = st0[b * kD + own_i];
  float p = st0[b * kD + kDQ + own_i];
  float tv = fast_tanh(q);

  if (lane < 8) q_l[own_i] = q;
  {
    float to = __shfl_xor(tv, 1);
    if (lane < 8 && !(lane & 1)) tq_l[0][4 * w + (lane >> 1)] = packh2(tv, to);
  }
  __syncthreads();
  // initial router logits q@Wq
  if (tid < 512) {
    int kk = tid >> 6, l2 = tid & 63;
    float2 qp = reinterpret_cast<const float2*>(q_l)[l2];
    float part = qp.x * wpx + qp.y * wpy;
    part += __shfl_xor(part, 1);  part += __shfl_xor(part, 2);
    part += __shfl_xor(part, 4);  part += __shfl_xor(part, 8);
    part += __shfl_xor(part, 16); part += __shfl_xor(part, 32);
    if (l2 == 0) wlog_l[kk] = part;
  }
  __syncthreads();

  // lane-constant selectors for force redistribution
  const bool selb1 = ((lane >> 1) & 1) != 0;
  const bool selb2 = ((lane >> 2) & 1) != 0;
  const bool selp  = (((lane & 1) ^ ((lane >> 4) & 1)) != 0);
  const bool hsel  = ((lane >> 5) & 1) != 0;   // k-half owned by this lane's accs

  int sb = 0;
  const int boff = b * kT;
  for (int t = 0; t < kT; t++) {
    const int bit = inputs[boff + t];
    const int task = task_ids[boff + t];
    const float u_own = u4_l[task * 2 + bit][own_i];
    f32x4 ctxA, ctxB;
    {
      const f32x4* cp = reinterpret_cast<const f32x4*>(&wq_ctx2[task][0]);
      ctxA = cp[0]; ctxB = cp[1];
    }

    for (int e = 0; e < kEVO; e++) {
      // ---- in-lane softmax over 8 router logits (all lanes, redundant) ----
      const f32x4* wl4 = reinterpret_cast<const f32x4*>(wlog_l);
      f32x4 lgA = wl4[0] + ctxA, lgB = wl4[1] + ctxB;
      float mx = fmaxf(fmaxf(fmaxf(lgA.x, lgA.y), fmaxf(lgA.z, lgA.w)),
                       fmaxf(fmaxf(lgB.x, lgB.y), fmaxf(lgB.z, lgB.w)));
      float e0 = __expf(lgA.x - mx), e1 = __expf(lgA.y - mx);
      float e2 = __expf(lgA.z - mx), e3 = __expf(lgA.w - mx);
      float e4 = __expf(lgB.x - mx), e5 = __expf(lgB.y - mx);
      float e6 = __expf(lgB.z - mx), e7 = __expf(lgB.w - mx);
      float inv = 1.f / (e0 + e1 + e2 + e3 + e4 + e5 + e6 + e7);
      float w0 = e0 * inv, w1 = e1 * inv, w2 = e2 * inv, w3 = e3 * inv;
      float w4 = e4 * inv, w5 = e5 * inv, w6 = e6 * inv, w7 = e7 * inv;
      float ws0 = hsel ? w4 : w0, ws1 = hsel ? w5 : w1;
      float ws2 = hsel ? w6 : w2, ws3 = hsel ? w7 : w3;

      // ---- MFMA: Y = A_flat @ tanh(q), B replicated across 16 cols ----
      const u32x4* tq4 = reinterpret_cast<const u32x4*>(tq_l[sb]);
      f32x4 ac0 = {0.f, 0.f, 0.f, 0.f}, ac1 = ac0, ac2 = ac0, ac3 = ac0;
      #pragma unroll
      for (int ks = 0; ks < 4; ks++) {
        half8 bf = __builtin_bit_cast(half8, tq4[4 * ks + g4]);
        ac0 = __builtin_amdgcn_mfma_f32_16x16x32_f16(__builtin_bit_cast(half8, afr[0][ks]), bf, ac0, 0, 0, 0);
        ac1 = __builtin_amdgcn_mfma_f32_16x16x32_f16(__builtin_bit_cast(half8, afr[1][ks]), bf, ac1, 0, 0, 0);
        ac2 = __builtin_amdgcn_mfma_f32_16x16x32_f16(__builtin_bit_cast(half8, afr[2][ks]), bf, ac2, 0, 0, 0);
        ac3 = __builtin_amdgcn_mfma_f32_16x16x32_f16(__builtin_bit_cast(half8, afr[3][ks]), bf, ac3, 0, 0, 0);
      }
      // ---- force[i] = sum_k w[k] Y[k,i]: 4 FMA + xor32 per mtile ----
      float f0 = ws0 * ac0.x + ws1 * ac0.y + ws2 * ac0.z + ws3 * ac0.w;
      float f1 = ws0 * ac1.x + ws1 * ac1.y + ws2 * ac1.z + ws3 * ac1.w;
      float f2 = ws0 * ac2.x + ws1 * ac2.y + ws2 * ac2.z + ws3 * ac2.w;
      float f3 = ws0 * ac3.x + ws1 * ac3.y + ws2 * ac3.z + ws3 * ac3.w;
      f0 += __shfl_xor(f0, 32); f1 += __shfl_xor(f1, 32);
      f2 += __shfl_xor(f2, 32); f3 += __shfl_xor(f3, 32);
      // redistribute so this lane gets force for its own i = 8w + (lane&7)
      float sA = selb2 ? (selb1 ? f3 : f2) : (selb1 ? f1 : f0);
      float sB = __shfl_xor(sA, 16);
      float force = selp ? sB : sA;

      // ---- state update (each lane owns one i; x8 redundant copies) ----
      float pn = (1.f - kDT * kDAMP) * p + kDT * (force + u_own);
      float tvp = fast_tanh(pn);
      q = q + kDT * tvp;
      p = pn;
      tv = fast_tanh(q);
      float to = __shfl_xor(tv, 1);
      if (lane < 8) {
        q_l[own_i] = q;
        if (!(lane & 1)) tq_l[sb ^ 1][4 * w + (lane >> 1)] = packh2(tv, to);
        if (e == kEVO - 1) p_l[own_i] = p;
      }
      if (e == kEVO - 1 && tid == 0) {
        chartw_l[0] = w0; chartw_l[1] = w1; chartw_l[2] = w2; chartw_l[3] = w3;
        chartw_l[4] = w4; chartw_l[5] = w5; chartw_l[6] = w6; chartw_l[7] = w7;
      }
      __syncthreads();
      // ---- router matvec wlog[k] = q_new @ Wq[:,k] (8 waves) ----
      if (tid < 512) {
        int kk = tid >> 6, l2 = tid & 63;
        float2 qp = reinterpret_cast<const float2*>(q_l)[l2];
        float part = qp.x * wpx + qp.y * wpy;
        part += __shfl_xor(part, 1);  part += __shfl_xor(part, 2);
        part += __shfl_xor(part, 4);  part += __shfl_xor(part, 8);
        part += __shfl_xor(part, 16); part += __shfl_xor(part, 32);
        if (l2 == 0) wlog_l[kk] = part;
      }
      sb ^= 1;
      __syncthreads();
    }

    // ---- decode: logits_k[pair] = state . rw[pair] (+rb) ----
    {
      int pair = tid >> 5, ln = tid & 31;
      const float* rwrow = &rw_l[pair * kD];
      float sacc = 0.f;
      #pragma unroll
      for (int m = 0; m < 8; m++) {
        int d = ln + 32 * m;
        float sv = (m < 4) ? q_l[d] : p_l[d - kDQ];
        sacc += sv * rwrow[d];
      }
      if (ln == 0) sacc += s_l * rwrow[256];
      sacc += __shfl_xor(sacc, 1); sacc += __shfl_xor(sacc, 2);
      sacc += __shfl_xor(sacc, 4); sacc += __shfl_xor(sacc, 8);
      sacc += __shfl_xor(sacc, 16);
      if (ln == 0) lk_l[pair] = sacc + rb_l[pair];
    }
    __syncthreads();
    // ---- scalar tail ----
    if (tid == 0) {
      const int tgt = targets[boff + t];
      const int prv = (t == 0) ? 0 : targets[boff + t - 1];
      float lg[kK]; float mx = -1e30f;
      #pragma unroll
      for (int kk = 0; kk < kK; kk++) { lg[kk] = wlog_l[kk] + wq_ctx2[task][kk]; mx = fmaxf(mx, lg[kk]); }
      float cw[kK]; float ssum = 0.f;
      #pragma unroll
      for (int kk = 0; kk < kK; kk++) { cw[kk] = expf(lg[kk] - mx); ssum += cw[kk]; }
      float invs = 1.f / ssum;
      #pragma unroll
      for (int kk = 0; kk < kK; kk++) cw[kk] *= invs;
      int i0 = 0; float v0 = cw[0];
      #pragma unroll
      for (int kk = 1; kk < kK; kk++) if (cw[kk] > v0) { v0 = cw[kk]; i0 = kk; }
      int i1 = (i0 == 0) ? 1 : 0; float v1 = cw[i1];
      #pragma unroll
      for (int kk = 0; kk < kK; kk++) if (kk != i0 && cw[kk] > v1) { v1 = cw[kk]; i1 = kk; }
      float wsum = fmaxf(v0 + v1, kEPS);
      float wn0 = v0 / wsum, wn1 = v1 / wsum;
      float lg4[4];
      #pragma unroll
      for (int v = 0; v < 4; v++) lg4[v] = wn0 * lk_l[i0 * 4 + v] + wn1 * lk_l[i1 * 4 + v];
      float m2 = fmaxf(lg4[0], lg4[1]);
      float lse2 = m2 + logf(expf(lg4[0] - m2) + expf(lg4[1] - m2));
      float m4 = fmaxf(fmaxf(lg4[0], lg4[1]), fmaxf(lg4[2], lg4[3]));
      float lse4 = m4 + logf(expf(lg4[0] - m4) + expf(lg4[1] - m4) + expf(lg4[2] - m4) + expf(lg4[3] - m4));
      int idx2 = (tgt < 1) ? tgt : 1;
      float p2 = (idx2 == 0) ? lg4[0] : lg4[1];
      float p4v = (tgt == 0) ? lg4[0] : ((tgt == 1) ? lg4[1] : ((tgt == 2) ? lg4[2] : lg4[3]));
      float ce2 = lse2 - p2, ce4 = lse4 - p4v;
      float pe = (task == 0) ? ce2 : ce4;
      int pred;
      if (task == 0) pred = (lg4[1] > lg4[0]) ? 1 : 0;
      else {
        pred = 0; float bv = lg4[0];
        if (lg4[1] > bv) { bv = lg4[1]; pred = 1; }
        if (lg4[2] > bv) { bv = lg4[2]; pred = 2; }
        if (lg4[3] > bv) { bv = lg4[3]; pred = 3; }
      }
      float corr = (pred == tgt) ? 1.f : 0.f;
      float csl = -logf(fmaxf(chartw_l[prv], kEPS));
      float Ft = kGAMMA * (pe + csl);
      acc_l[0] += Ft; acc_l[1] += corr; acc_l[2] += pe;
      #pragma unroll
      for (int kk = 0; kk < kK; kk++) acc_l[3 + kk] += chartw_l[kk];
      acc_l[11 + task] += corr; acc_l[13 + task] += 1.f;
      if (task == 1) {
        #pragma unroll
        for (int kk = 0; kk < kK; kk++) acc_l[15 + prv * kK + kk] += chartw_l[kk];
        acc_l[47 + prv] += 1.f;
      }
    }
    __syncthreads();
  }

  if (tid < 64) ws[b * 64 + tid] = acc_l[tid];
}

extern "C" __global__ void seq_finalize(const float* __restrict__ ws, float* __restrict__ out) {
  const int tid = threadIdx.x;
  __shared__ float red[51];
  if (tid < 51) {
    float s = 0.f;
    for (int b = 0; b < 256; b++) s += ws[b * 64 + tid];
    red[tid] = s;
  }
  __syncthreads();
  if (tid == 0) {
    const float BT = 256.f * 32.f;
    out[0] = red[0] / BT;
    out[1] = red[1] / BT;
    out[2] = red[2] / BT;
    float us = 0.f;
    for (int k = 0; k < 8; k++) { out[3 + k] = red[3 + k]; us += red[3 + k]; }
    float ent = 0.f;
    for (int k = 0; k < 8; k++) {
      float dist = red[3 + k] / (us + kEPS);
      ent -= dist * logf(dist + kEPS);
    }
    out[11] = ent;
    out[12] = red[11] / (red[13] + kEPS);
    out[13] = red[12] / (red[14] + kEPS);
    float tot = 0.f;
    for (int j = 0; j < 32; j++) { out[14 + j] = red[15 + j]; tot += red[15 + j]; }
    for (int s2 = 0; s2 < 4; s2++) out[46 + s2] = red[47 + s2];
    float inv = 1.f / (tot + kEPS);
    float ps[4] = {0.f, 0.f, 0.f, 0.f};
    float pc[8] = {0.f, 0.f, 0.f, 0.f, 0.f, 0.f, 0.f, 0.f};
    for (int s2 = 0; s2 < 4; s2++)
      for (int k = 0; k < 8; k++) {
        float jv = red[15 + s2 * 8 + k] * inv;
        ps[s2] += jv; pc[k] += jv;
      }
    float mi = 0.f;
    for (int s2 = 0; s2 < 4; s2++)
      for (int k = 0; k < 8; k++) {
        float jv = red[15 + s2 * 8 + k] * inv;
        mi += jv * (logf(jv + kEPS) - logf(ps[s2] + kEPS) - logf(pc[k] + kEPS));
      }
    mi = (tot > 0.f) ? fmaxf(mi, 0.f) : 0.f;
    out[50] = mi;
  }
}

extern "C" void kernel_launch(void* const* d_in, const int* in_sizes, int n_in,
                              void* d_out, int out_size, void* d_ws, size_t ws_size,
                              hipStream_t stream) {
  (void)in_sizes; (void)n_in; (void)out_size; (void)ws_size;
  const int* inputs   = (const int*)d_in[0];
  const int* targets  = (const int*)d_in[1];
  const int* task_ids = (const int*)d_in[2];
  const float* st0      = (const float*)d_in[3];
  const float* bit_emb  = (const float*)d_in[4];
  const float* task_u   = (const float*)d_in[5];
  const float* ctx_emb  = (const float*)d_in[6];
  const float* rw       = (const float*)d_in[7];
  const float* rb       = (const float*)d_in[8];
  const float* Wq       = (const float*)d_in[9];
  const float* Wc       = (const float*)d_in[10];
  const float* bb       = (const float*)d_in[11];
  const float* A        = (const float*)d_in[12];
  float* ws  = (float*)d_ws;
  float* out = (float*)d_out;
  hipLaunchKernelGGL(seq_main, dim3(256), dim3(1024), 0, stream,
                     inputs, targets, task_ids, st0, bit_emb, task_u, ctx_emb,
                     rw, rb, Wq, Wc, bb, A, ws);
  hipLaunchKernelGGL(seq_finalize, dim3(1), dim3(64), 0, stream, ws, out);
}

// Round 3
// 411.992 us; speedup vs baseline: 1.2916x; 1.2916x over previous
//
#include <hip/hip_runtime.h>
#include <hip/hip_fp16.h>

namespace {
constexpr int kT = 32, kDQ = 128, kK = 8, kS = 4, kCTX = 16, kD = 257, kEVO = 8;
constexpr float kDT = 0.2f, kDAMP = 0.1f, kGAMMA = 10.0f, kEPS = 1e-8f;

typedef _Float16 half8 __attribute__((ext_vector_type(8)));
typedef float f32x4 __attribute__((ext_vector_type(4)));
typedef unsigned u32x4 __attribute__((ext_vector_type(4)));

__device__ __forceinline__ unsigned packh2(float lo, float hi) {
  __half l = __float2half(lo), h = __float2half(hi);
  return (unsigned)__half_as_ushort(l) | ((unsigned)__half_as_ushort(h) << 16);
}
__device__ __forceinline__ float fast_tanh(float x) {
  float e = __expf(2.f * x);
  return 1.f - 2.f / (e + 1.f);
}
}  // namespace

extern "C" __global__ void __launch_bounds__(512, 2)
seq_main(const int* __restrict__ inputs, const int* __restrict__ targets,
         const int* __restrict__ task_ids, const float* __restrict__ st0,
         const float* __restrict__ bit_emb, const float* __restrict__ task_u,
         const float* __restrict__ ctx_emb, const float* __restrict__ rw_g,
         const float* __restrict__ rb_g, const float* __restrict__ Wq_g,
         const float* __restrict__ Wc_g, const float* __restrict__ b_g,
         const float* __restrict__ A_g, float* __restrict__ ws) {
  const int tid = threadIdx.x, b = blockIdx.x;
  const int lane = tid & 63, w = tid >> 6;
  const int g = lane >> 4, c = lane & 15;     // acc group / col
  const int g2 = lane >> 3, j = lane & 7;     // router group (k) / lane-in-group
  const int i_own = 16 * w + c;               // owned state index (4 copies over g)

  __shared__ __align__(16) float rw_l[kK * kS * kD];
  __shared__ __align__(16) float u4_l[4][kDQ];
  __shared__ __align__(16) float q_l[2][kDQ];
  __shared__ __align__(16) float p_l[kDQ];
  __shared__ __align__(16) unsigned tq_l[2][64];   // tanh(q) fp16-packed, ping-pong
  __shared__ __align__(16) float wq_ctx2[2][kK];
  __shared__ float chartw_l[kK];   // softmax consumed at evo step 7 (= ws[-1])
  __shared__ float cwnext_l[kK];   // softmax(router(q_final)) for decode
  __shared__ float rb_l[kK * kS];
  __shared__ float lk_l[kK * kS];
  __shared__ float acc_l[64];
  __shared__ float s_l;

  // ---------- init tables ----------
  for (int idx = tid; idx < kK * kS * kD; idx += 512) rw_l[idx] = rw_g[idx];
  if (tid < kK * kS) rb_l[tid] = rb_g[tid];
  if (tid == 0) s_l = st0[b * kD + 2 * kDQ];
  if (tid < 64) acc_l[tid] = 0.f;
  {
    int cb = tid >> 7, i = tid & 127;  // 512 threads = 4 combos x 128
    u4_l[cb][i] = tanhf(bit_emb[(cb & 1) * kDQ + i]) + tanhf(task_u[(cb >> 1) * kDQ + i]);
  }
  if (tid < 16) {
    int tk = tid >> 3, kk = tid & 7;
    float s = b_g[kk];
    #pragma unroll
    for (int cc = 0; cc < kCTX; cc++) s += tanhf(ctx_emb[tk * kCTX + cc]) * Wc_g[cc * kK + kk];
    wq_ctx2[tk][kk] = s;
  }

  // ---------- A fragments (fp16) in registers: 8 m-tiles x 4 k-steps ----------
  // m-tile mt covers rows (k,i): k=(c&3)+4*((c>>3)&1), i=16w+2mt+((c>>2)&1)
  const int kA = (c & 3) + 4 * ((c >> 3) & 1);
  const int ipar = (c >> 2) & 1;
  u32x4 afr[8][4];
  #pragma unroll
  for (int mt = 0; mt < 8; mt++) {
    const float* arow = A_g + ((size_t)kA * kDQ + (16 * w + 2 * mt + ipar)) * kDQ;
    #pragma unroll
    for (int ks = 0; ks < 4; ks++) {
      const float4* p4 = reinterpret_cast<const float4*>(arow + 32 * ks + 8 * g);
      float4 f0 = p4[0], f1 = p4[1];
      u32x4 v;
      v.x = packh2(f0.x, f0.y); v.y = packh2(f0.z, f0.w);
      v.z = packh2(f1.x, f1.y); v.w = packh2(f1.z, f1.w);
      afr[mt][ks] = v;
    }
  }
  // Router weights: lane (g2,j) covers i = 16j..16j+15 for k = g2
  float wqr[16];
  #pragma unroll
  for (int m = 0; m < 16; m++) wqr[m] = Wq_g[(16 * j + m) * kK + g2];

  // ---------- persistent per-lane state ----------
  float q = st0[b * kD + i_own];
  float p = st0[b * kD + kDQ + i_own];
  if (g == 0) {
    q_l[0][i_own] = q;
    float tv = fast_tanh(q);
    float to = __shfl_xor(tv, 1);
    if (!(c & 1)) tq_l[0][i_own >> 1] = packh2(tv, to);
  }
  __syncthreads();

  const float ctx0k = wq_ctx2[0][g2], ctx1k = wq_ctx2[1][g2];
  const int srl0 = 32 * (lane >> 5) + j;  // shfl src base for ws fetch (k = 4h+s)
  const int boff = b * kT;

  // router dot: wlog[g2] computed by all lanes of group g2 (butterfly)
  auto rdot = [&](const float* qb) -> float {
    const float4* q4 = reinterpret_cast<const float4*>(qb + 16 * j);
    float4 a0 = q4[0], a1 = q4[1], a2 = q4[2], a3 = q4[3];
    float part = a0.x * wqr[0] + a0.y * wqr[1] + a0.z * wqr[2] + a0.w * wqr[3]
               + a1.x * wqr[4] + a1.y * wqr[5] + a1.z * wqr[6] + a1.w * wqr[7]
               + a2.x * wqr[8] + a2.y * wqr[9] + a2.z * wqr[10] + a2.w * wqr[11]
               + a3.x * wqr[12] + a3.y * wqr[13] + a3.z * wqr[14] + a3.w * wqr[15];
    part += __shfl_xor(part, 1); part += __shfl_xor(part, 2); part += __shfl_xor(part, 4);
    return part;
  };
  // lane-packed softmax across k (xor 8/16/32): one exp per wave
  auto rsmax = [&](float wlog, float ctxk) -> float {
    float lg = wlog + ctxk;
    float mx = lg;
    mx = fmaxf(mx, __shfl_xor(mx, 8));
    mx = fmaxf(mx, __shfl_xor(mx, 16));
    mx = fmaxf(mx, __shfl_xor(mx, 32));
    float ex = __expf(lg - mx);
    float sm = ex;
    sm += __shfl_xor(sm, 8); sm += __shfl_xor(sm, 16); sm += __shfl_xor(sm, 32);
    return ex / sm;
  };

  // pre-loop router: ws for (t=0, e=0)
  float ws0, ws1, ws2, ws3;
  {
    const int task0 = task_ids[boff];
    float wlog = rdot(q_l[0]);
    float wv = rsmax(wlog, task0 ? ctx1k : ctx0k);
    ws0 = __shfl(wv, srl0);      ws1 = __shfl(wv, srl0 + 8);
    ws2 = __shfl(wv, srl0 + 16); ws3 = __shfl(wv, srl0 + 24);
  }

  int sb = 0;
  for (int t = 0; t < kT; t++) {
    const int bit = inputs[boff + t];
    const int task = task_ids[boff + t];
    const int tasknx = (t < kT - 1) ? task_ids[boff + t + 1] : 0;
    const float u_own = u4_l[task * 2 + bit][i_own];

    for (int e = 0; e < kEVO; e++) {
      // ---- X: MFMA matvec + weighted combine + state update ----
      const u32x4* tq4 = reinterpret_cast<const u32x4*>(tq_l[sb]);
      f32x4 ac[8];
      #pragma unroll
      for (int mt = 0; mt < 8; mt++) ac[mt] = f32x4{0.f, 0.f, 0.f, 0.f};
      #pragma unroll
      for (int ks = 0; ks < 4; ks++) {
        half8 bf = __builtin_bit_cast(half8, tq4[4 * ks + g]);
        #pragma unroll
        for (int mt = 0; mt < 8; mt++)
          ac[mt] = __builtin_amdgcn_mfma_f32_16x16x32_f16(
              __builtin_bit_cast(half8, afr[mt][ks]), bf, ac[mt], 0, 0, 0);
      }
      float f0_, f1_, f2_, f3_, f4_, f5_, f6_, f7_;
      {
        float tmp[8];
        #pragma unroll
        for (int mt = 0; mt < 8; mt++) {
          float v = ws0 * ac[mt].x + ws1 * ac[mt].y + ws2 * ac[mt].z + ws3 * ac[mt].w;
          v += __shfl_xor(v, 32);   // sum k-halves
          tmp[mt] = v;
        }
        f0_ = tmp[0]; f1_ = tmp[1]; f2_ = tmp[2]; f3_ = tmp[3];
        f4_ = tmp[4]; f5_ = tmp[5]; f6_ = tmp[6]; f7_ = tmp[7];
      }
      // select force[i_own]: mt = c>>1, parity fix via xor16
      const bool s0 = ((c >> 1) & 1), s1 = ((c >> 2) & 1), s2 = ((c >> 3) & 1);
      float a0 = s0 ? f1_ : f0_, a1 = s0 ? f3_ : f2_;
      float a2 = s0 ? f5_ : f4_, a3 = s0 ? f7_ : f6_;
      float b0 = s1 ? a1 : a0, b1 = s1 ? a3 : a2;
      float sel = s2 ? b1 : b0;
      float oth = __shfl_xor(sel, 16);
      float force = ((c ^ g) & 1) ? oth : sel;

      float pn = (1.f - kDT * kDAMP) * p + kDT * (force + u_own);
      q = q + kDT * fast_tanh(pn);
      p = pn;
      float tv = fast_tanh(q);
      if (g == 0) {
        float to = __shfl_xor(tv, 1);
        q_l[sb ^ 1][i_own] = q;
        if (!(c & 1)) tq_l[sb ^ 1][i_own >> 1] = packh2(tv, to);
        if (e == kEVO - 1) p_l[i_own] = p;
      }
      __syncthreads();

      // ---- R: router + lane-packed softmax (produces ws for next X) ----
      float wlog = rdot(q_l[sb ^ 1]);
      float ctxn = (e < kEVO - 1) ? (task ? ctx1k : ctx0k) : (tasknx ? ctx1k : ctx0k);
      float wv = rsmax(wlog, ctxn);
      ws0 = __shfl(wv, srl0);      ws1 = __shfl(wv, srl0 + 8);
      ws2 = __shfl(wv, srl0 + 16); ws3 = __shfl(wv, srl0 + 24);
      if (e == kEVO - 2 && w == 0 && j == 0) chartw_l[g2] = wv;  // ws[-1]
      if (e == kEVO - 1) {
        float wvc = rsmax(wlog, task ? ctx1k : ctx0k);  // chart_w_next (current ctx)
        if (w == 0 && j == 0) cwnext_l[g2] = wvc;
      }
      sb ^= 1;
    }

    __syncthreads();
    // ---- decode: logits_k[pair] = state . rw[pair] (+rb); 32 pairs x 16 lanes ----
    {
      int pair = tid >> 4, ln = tid & 15;
      const float* rwrow = &rw_l[pair * kD];
      float sacc = 0.f;
      #pragma unroll
      for (int m = 0; m < 16; m++) {
        int d = ln + 16 * m;
        float sv = (m < 8) ? q_l[0][d] : p_l[d - kDQ];
        sacc += sv * rwrow[d];
      }
      if (ln == 0) sacc += s_l * rwrow[256];
      sacc += __shfl_xor(sacc, 1); sacc += __shfl_xor(sacc, 2);
      sacc += __shfl_xor(sacc, 4); sacc += __shfl_xor(sacc, 8);
      if (ln == 0) lk_l[pair] = sacc + rb_l[pair];
    }
    __syncthreads();
    // ---- scalar tail ----
    if (tid == 0) {
      const int tgt = targets[boff + t];
      const int prv = (t == 0) ? 0 : targets[boff + t - 1];
      float cw[kK];
      #pragma unroll
      for (int kk = 0; kk < kK; kk++) cw[kk] = cwnext_l[kk];
      int i0 = 0; float v0 = cw[0];
      #pragma unroll
      for (int kk = 1; kk < kK; kk++) if (cw[kk] > v0) { v0 = cw[kk]; i0 = kk; }
      int i1 = (i0 == 0) ? 1 : 0; float v1 = cw[i1];
      #pragma unroll
      for (int kk = 0; kk < kK; kk++) if (kk != i0 && cw[kk] > v1) { v1 = cw[kk]; i1 = kk; }
      float wsum = fmaxf(v0 + v1, kEPS);
      float wn0 = v0 / wsum, wn1 = v1 / wsum;
      float lg4[4];
      #pragma unroll
      for (int v = 0; v < 4; v++) lg4[v] = wn0 * lk_l[i0 * 4 + v] + wn1 * lk_l[i1 * 4 + v];
      float m2 = fmaxf(lg4[0], lg4[1]);
      float lse2 = m2 + logf(expf(lg4[0] - m2) + expf(lg4[1] - m2));
      float m4 = fmaxf(fmaxf(lg4[0], lg4[1]), fmaxf(lg4[2], lg4[3]));
      float lse4 = m4 + logf(expf(lg4[0] - m4) + expf(lg4[1] - m4) + expf(lg4[2] - m4) + expf(lg4[3] - m4));
      int idx2 = (tgt < 1) ? tgt : 1;
      float p2 = (idx2 == 0) ? lg4[0] : lg4[1];
      float p4v = (tgt == 0) ? lg4[0] : ((tgt == 1) ? lg4[1] : ((tgt == 2) ? lg4[2] : lg4[3]));
      float ce2 = lse2 - p2, ce4 = lse4 - p4v;
      float pe = (task == 0) ? ce2 : ce4;
      int pred;
      if (task == 0) pred = (lg4[1] > lg4[0]) ? 1 : 0;
      else {
        pred = 0; float bv = lg4[0];
        if (lg4[1] > bv) { bv = lg4[1]; pred = 1; }
        if (lg4[2] > bv) { bv = lg4[2]; pred = 2; }
        if (lg4[3] > bv) { bv = lg4[3]; pred = 3; }
      }
      float corr = (pred == tgt) ? 1.f : 0.f;
      float csl = -logf(fmaxf(chartw_l[prv], kEPS));
      float Ft = kGAMMA * (pe + csl);
      acc_l[0] += Ft; acc_l[1] += corr; acc_l[2] += pe;
      #pragma unroll
      for (int kk = 0; kk < kK; kk++) acc_l[3 + kk] += chartw_l[kk];
      acc_l[11 + task] += corr; acc_l[13 + task] += 1.f;
      if (task == 1) {
        #pragma unroll
        for (int kk = 0; kk < kK; kk++) acc_l[15 + prv * kK + kk] += chartw_l[kk];
        acc_l[47 + prv] += 1.f;
      }
    }
    __syncthreads();
  }

  __syncthreads();
  if (tid < 64) ws[b * 64 + tid] = acc_l[tid];
}

extern "C" __global__ void seq_finalize(const float* __restrict__ ws, float* __restrict__ out) {
  const int tid = threadIdx.x;
  __shared__ float red[51];
  if (tid < 51) {
    float s = 0.f;
    for (int b = 0; b < 256; b++) s += ws[b * 64 + tid];
    red[tid] = s;
  }
  __syncthreads();
  if (tid == 0) {
    const float BT = 256.f * 32.f;
    out[0] = red[0] / BT;
    out[1] = red[1] / BT;
    out[2] = red[2] / BT;
    float us = 0.f;
    for (int k = 0; k < 8; k++) { out[3 + k] = red[3 + k]; us += red[3 + k]; }
    float ent = 0.f;
    for (int k = 0; k < 8; k++) {
      float dist = red[3 + k] / (us + kEPS);
      ent -= dist * logf(dist + kEPS);
    }
    out[11] = ent;
    out[12] = red[11] / (red[13] + kEPS);
    out[13] = red[12] / (red[14] + kEPS);
    float tot = 0.f;
    for (int jj = 0; jj < 32; jj++) { out[14 + jj] = red[15 + jj]; tot += red[15 + jj]; }
    for (int s2 = 0; s2 < 4; s2++) out[46 + s2] = red[47 + s2];
    float inv = 1.f / (tot + kEPS);
    float ps[4] = {0.f, 0.f, 0.f, 0.f};
    float pc[8] = {0.f, 0.f, 0.f, 0.f, 0.f, 0.f, 0.f, 0.f};
    for (int s2 = 0; s2 < 4; s2++)
      for (int k = 0; k < 8; k++) {
        float jv = red[15 + s2 * 8 + k] * inv;
        ps[s2] += jv; pc[k] += jv;
      }
    float mi = 0.f;
    for (int s2 = 0; s2 < 4; s2++)
      for (int k = 0; k < 8; k++) {
        float jv = red[15 + s2 * 8 + k] * inv;
        mi += jv * (logf(jv + kEPS) - logf(ps[s2] + kEPS) - logf(pc[k] + kEPS));
      }
    mi = (tot > 0.f) ? fmaxf(mi, 0.f) : 0.f;
    out[50] = mi;
  }
}

extern "C" void kernel_launch(void* const* d_in, const int* in_sizes, int n_in,
                              void* d_out, int out_size, void* d_ws, size_t ws_size,
                              hipStream_t stream) {
  (void)in_sizes; (void)n_in; (void)out_size; (void)ws_size;
  const int* inputs   = (const int*)d_in[0];
  const int* targets  = (const int*)d_in[1];
  const int* task_ids = (const int*)d_in[2];
  const float* st0      = (const float*)d_in[3];
  const float* bit_emb  = (const float*)d_in[4];
  const float* task_u   = (const float*)d_in[5];
  const float* ctx_emb  = (const float*)d_in[6];
  const float* rw       = (const float*)d_in[7];
  const float* rb       = (const float*)d_in[8];
  const float* Wq       = (const float*)d_in[9];
  const float* Wc       = (const float*)d_in[10];
  const float* bb       = (const float*)d_in[11];
  const float* A        = (const float*)d_in[12];
  float* ws  = (float*)d_ws;
  float* out = (float*)d_out;
  hipLaunchKernelGGL(seq_main, dim3(256), dim3(512), 0, stream,
                     inputs, targets, task_ids, st0, bit_emb, task_u, ctx_emb,
                     rw, rb, Wq, Wc, bb, A, ws);
  hipLaunchKernelGGL(seq_finalize, dim3(1), dim3(64), 0, stream, ws, out);
}